// Round 7
// baseline (10565.053 us; speedup 1.0000x reference)
//
#include <hip/hip_runtime.h>
#include <stdint.h>

#define TT 512
#define BB 64
#define II 256
#define HS 512          // H
#define HHALF 256       // HH
#define R4H 2048        // 4*H
#define HB_STRIDE 16384 // (HS/2)*BB u32 entries per h buffer

// ---------------------------------------------------------------------------
// Phase 1: PG[t][r][b] = (b_ih[r]+b_hh[r]) + sum_k W_ih[r][k] * X[b][t][k]
// ---------------------------------------------------------------------------
__global__ __launch_bounds__(256) void pregemm(
    const float* __restrict__ X,    // [B][T][I]
    const float* __restrict__ Wih,  // [4H][I]
    const float* __restrict__ bih,
    const float* __restrict__ bhh,
    float* __restrict__ PG)         // [T][4H][B]
{
  __shared__ __align__(16) float Xs[64][68];
  __shared__ __align__(16) float Ws[64][68];
  const int t = blockIdx.x;
  const int rbase = blockIdx.y * 64;
  const int tid = threadIdx.x;
  const int cg = tid & 15;
  const int rg = tid >> 4;

  float acc[4][4] = {};

  for (int k0 = 0; k0 < II; k0 += 64) {
    {
      int b = tid >> 2, kq = tid & 3;
      const float* src = X + ((size_t)b * TT + t) * II + k0 + kq * 16;
      #pragma unroll
      for (int i = 0; i < 16; i += 4) {
        float4 v = *(const float4*)(src + i);
        int kk = kq * 16 + i;
        Xs[kk + 0][b] = v.x; Xs[kk + 1][b] = v.y;
        Xs[kk + 2][b] = v.z; Xs[kk + 3][b] = v.w;
      }
    }
    {
      int r = tid >> 2, kq = tid & 3;
      const float* src = Wih + (size_t)(rbase + r) * II + k0 + kq * 16;
      #pragma unroll
      for (int i = 0; i < 16; i += 4) {
        float4 v = *(const float4*)(src + i);
        int kk = kq * 16 + i;
        Ws[kk + 0][r] = v.x; Ws[kk + 1][r] = v.y;
        Ws[kk + 2][r] = v.z; Ws[kk + 3][r] = v.w;
      }
    }
    __syncthreads();
    #pragma unroll 8
    for (int kk = 0; kk < 64; ++kk) {
      float4 a = *(const float4*)&Ws[kk][rg * 4];
      float4 x = *(const float4*)&Xs[kk][cg * 4];
      float av[4] = {a.x, a.y, a.z, a.w};
      float xv[4] = {x.x, x.y, x.z, x.w};
      #pragma unroll
      for (int i = 0; i < 4; ++i)
        #pragma unroll
        for (int j = 0; j < 4; ++j)
          acc[i][j] = fmaf(av[i], xv[j], acc[i][j]);
    }
    __syncthreads();
  }

  #pragma unroll
  for (int i = 0; i < 4; ++i) {
    int row = rbase + rg * 4 + i;
    float bias = bih[row] + bhh[row];
    float4 o;
    o.x = acc[i][0] + bias; o.y = acc[i][1] + bias;
    o.z = acc[i][2] + bias; o.w = acc[i][3] + bias;
    *(float4*)&PG[((size_t)t * R4H + row) * BB + cg * 4] = o;
  }
}

// ---------------------------------------------------------------------------
// bf16 round-to-nearest-even (h magnitudes are finite, |h|<=1; no NaN path)
// ---------------------------------------------------------------------------
__device__ __forceinline__ uint32_t bf16r(float f) {
  uint32_t u = __float_as_uint(f);
  u += 0x7fffu + ((u >> 16) & 1u);
  return u >> 16;
}

// init: hb[0][uh][b] = pack(bf16(mem[b][256+2uh]), bf16(mem[b][256+2uh+1]))
__global__ void init_h(const float* __restrict__ mem, uint32_t* __restrict__ hb)
{
  int idx = blockIdx.x * 256 + threadIdx.x;
  if (idx < HB_STRIDE) {
    int uh = idx >> 6, b = idx & 63;
    float lo = mem[(size_t)b * 1280 + 256 + 2 * uh];
    float hi = mem[(size_t)b * 1280 + 256 + 2 * uh + 1];
    hb[idx] = bf16r(lo) | (bf16r(hi) << 16);
  }
}

// ---------------------------------------------------------------------------
// Cross-XCD h hand-off (proven in R6): relaxed agent-scope EXCHANGE stores
// (RMW performed at the IF coherence point; vmcnt(0) ack => globally
// visible) + relaxed agent-scope loads (bypass stale L1/L2). RELAXED =>
// no wbl2/inv sweeps.
// ---------------------------------------------------------------------------
__device__ __forceinline__ void store_coh_u32(uint32_t* p, uint32_t v) {
  (void)__hip_atomic_exchange(p, v, __ATOMIC_RELAXED, __HIP_MEMORY_SCOPE_AGENT);
}
__device__ __forceinline__ uint32_t load_coh_u32(const uint32_t* p) {
  return __hip_atomic_load(p, __ATOMIC_RELAXED, __HIP_MEMORY_SCOPE_AGENT);
}

// ---------------------------------------------------------------------------
// Persistent LSTM. grid = 256 WGs x 512 threads; WG g owns units {2g, 2g+1}.
// lane = batch element; wave w owns k-chunk [w*64, w*64+64).
// W_hh values are wave-uniform -> scalar loads (s_load), FMA = v_fmac v,s,v.
// h is bf16x2-packed (unit-pairs) -> half the coherent-load traffic.
// Barrier: hierarchical monotonic counters, relaxed agent RMWs (proven R6).
// ---------------------------------------------------------------------------
__global__ __launch_bounds__(512) void lstm_persistent(
    const float* __restrict__ mem,   // [B][1280]
    const float* __restrict__ Whh,   // [4H][H]
    float* __restrict__ PG,          // [T][4H][B]
    uint32_t* __restrict__ hb,       // [2][HS/2][B] packed bf16x2
    float* __restrict__ outmem,      // [B][1280]
    unsigned* __restrict__ bar)      // grpcnt[8]@stride64, cnt2@1024, gen@1088
{
  const int g = blockIdx.x;
  const int u0 = g * 2;
  const int tid = threadIdx.x;
  const int wu = __builtin_amdgcn_readfirstlane(tid >> 6);  // wave id, uniform
  const int lane = tid & 63;

  __shared__ float part[8][64][9];
  __shared__ float gsum[8][64];

  unsigned* grpcnt = bar + (g >> 5) * 64;
  unsigned* cnt2   = bar + 1024;
  unsigned* gen    = bar + 1088;

  // Uniform row-base pointers for this wave's W slice (8 gate rows x 64 k).
  const float* wrb[8];
  #pragma unroll
  for (int r = 0; r < 8; ++r)
    wrb[r] = Whh + (size_t)((r >> 1) * HS + u0 + (r & 1)) * HS + wu * 64;

  // per-batch state: tid<64 owns batch b=tid, BOTH units {u0, u0+1}
  float c0 = 0.f, c1 = 0.f, m0 = 0.f, m1 = 0.f, h0l = 0.f, h1l = 0.f;
  if (tid < 64) {
    c0 = mem[(size_t)tid * 1280 + 768 + u0];
    c1 = mem[(size_t)tid * 1280 + 768 + u0 + 1];
    if (u0 < HHALF) {
      m0 = mem[(size_t)tid * 1280 + u0];
      m1 = mem[(size_t)tid * 1280 + u0 + 1];
    }
  }

  const int rr = tid >> 6;
  const int grow = (rr >> 1) * HS + u0 + (rr & 1);

  for (int t = 0; t < TT; ++t) {
    const uint32_t* hcur = hb + (size_t)(t & 1) * HB_STRIDE;
    float pg = PG[((size_t)t * R4H + grow) * BB + lane];

    // ---- fetch this wave's packed h chunk (coherent, all in flight) ----
    const uint32_t* hp = hcur + (size_t)(wu * 32) * BB + lane;
    uint32_t hpk[32];
    #pragma unroll
    for (int j = 0; j < 32; ++j) hpk[j] = load_coh_u32(hp + (size_t)j * BB);
    float hreg[64];
    #pragma unroll
    for (int j = 0; j < 32; ++j) {
      hreg[2 * j]     = __int_as_float(hpk[j] << 16);
      hreg[2 * j + 1] = __int_as_float(hpk[j] & 0xffff0000u);
    }

    // ---- recurrent GEMM: W uniform (s_load/SGPR), h per-lane (VGPR) ----
    float acc[8] = {0, 0, 0, 0, 0, 0, 0, 0};
    #pragma unroll
    for (int kk = 0; kk < 64; ++kk) {
      float h = hreg[kk];
      #pragma unroll
      for (int r = 0; r < 8; ++r)
        acc[r] = fmaf(wrb[r][kk], h, acc[r]);
    }
    #pragma unroll
    for (int r = 0; r < 8; ++r) part[r][lane][wu] = acc[r];
    __syncthreads();

    // ---- reduce 8 k-chunk partials + pg ----
    float s = pg;
    #pragma unroll
    for (int ww = 0; ww < 8; ++ww) s += part[rr][lane][ww];
    gsum[rr][lane] = s;
    __syncthreads();

    // ---- elementwise LSTM cells (both units) + cmax (tid < 64) ----
    if (tid < 64) {
      const int b = tid;
      float gi0 = gsum[0][b], gf0 = gsum[2][b], gg0 = gsum[4][b], go0 = gsum[6][b];
      float gi1 = gsum[1][b], gf1 = gsum[3][b], gg1 = gsum[5][b], go1 = gsum[7][b];
      float si0 = 1.f / (1.f + __expf(-gi0));
      float sf0 = 1.f / (1.f + __expf(-gf0));
      float so0 = 1.f / (1.f + __expf(-go0));
      float si1 = 1.f / (1.f + __expf(-gi1));
      float sf1 = 1.f / (1.f + __expf(-gf1));
      float so1 = 1.f / (1.f + __expf(-go1));
      c0 = sf0 * c0 + si0 * tanhf(gg0);
      c1 = sf1 * c1 + si1 * tanhf(gg1);
      float h0 = so0 * tanhf(c0);
      float h1 = so1 * tanhf(c1);
      h0l = h0; h1l = h1;
      store_coh_u32(&hb[(size_t)((t + 1) & 1) * HB_STRIDE + (size_t)g * 64 + b],
                    bf16r(h0) | (bf16r(h1) << 16));
      float out0, out1;
      if (u0 < HHALF) { m0 = fmaxf(m0, h0); m1 = fmaxf(m1, h1); out0 = m0; out1 = m1; }
      else            { out0 = h0; out1 = h1; }
      PG[((size_t)t * R4H + u0) * BB + b]     = out0;  // same-WG rows only
      PG[((size_t)t * R4H + u0 + 1) * BB + b] = out1;
    }

    // ---- device barrier: release = vmcnt(0) on the exchange h-stores ----
    asm volatile("s_waitcnt vmcnt(0)" ::: "memory");
    __syncthreads();
    if (tid == 0) {
      unsigned tgt1 = 32u * (unsigned)(t + 1);
      unsigned a = __hip_atomic_fetch_add(grpcnt, 1u, __ATOMIC_RELAXED,
                                          __HIP_MEMORY_SCOPE_AGENT);
      if (a == tgt1 - 1u) {
        unsigned b2 = __hip_atomic_fetch_add(cnt2, 1u, __ATOMIC_RELAXED,
                                             __HIP_MEMORY_SCOPE_AGENT);
        if (b2 == 8u * (unsigned)(t + 1) - 1u)
          (void)__hip_atomic_exchange(gen, (unsigned)(t + 1), __ATOMIC_RELAXED,
                                      __HIP_MEMORY_SCOPE_AGENT);
      }
      // failsafe cap: fast wrong-answer instead of a hang; expected wait ~us.
      int spins = 0;
      while (__hip_atomic_load(gen, __ATOMIC_RELAXED,
                               __HIP_MEMORY_SCOPE_AGENT) < (unsigned)(t + 1)) {
        __builtin_amdgcn_s_sleep(2);
        if (++spins > (1 << 16)) break;
      }
    }
    __syncthreads();
  }

  if (tid < 64) {
    outmem[(size_t)tid * 1280 + 256 + u0]     = h0l;
    outmem[(size_t)tid * 1280 + 256 + u0 + 1] = h1l;
    outmem[(size_t)tid * 1280 + 768 + u0]     = c0;
    outmem[(size_t)tid * 1280 + 768 + u0 + 1] = c1;
    if (u0 < HHALF) {
      outmem[(size_t)tid * 1280 + u0]     = m0;
      outmem[(size_t)tid * 1280 + u0 + 1] = m1;
    }
  }
}

// ---------------------------------------------------------------------------
// Phase 3: out[b][t][u] = PG[t][u][b]  (u < 512)
// ---------------------------------------------------------------------------
__global__ __launch_bounds__(256) void transpose_out(
    const float* __restrict__ PG, float* __restrict__ out)
{
  __shared__ __align__(16) float tileS[64][68];
  const int t = blockIdx.x;
  const int u0 = blockIdx.y * 64;
  const int tid = threadIdx.x;

  {
    int cg = tid & 15, rg = tid >> 4;
    const float* src = PG + (size_t)t * R4H * BB + (size_t)u0 * BB;
    #pragma unroll
    for (int i = 0; i < 4; ++i) {
      int u = rg * 4 + i;
      float4 v = *(const float4*)(src + (size_t)u * BB + cg * 4);
      *(float4*)&tileS[u][cg * 4] = v;
    }
  }
  __syncthreads();
  {
    int ug = tid & 15, bg = tid >> 4;
    #pragma unroll
    for (int i = 0; i < 4; ++i) {
      int b = bg * 4 + i;
      float4 o;
      o.x = tileS[ug * 4 + 0][b];
      o.y = tileS[ug * 4 + 1][b];
      o.z = tileS[ug * 4 + 2][b];
      o.w = tileS[ug * 4 + 3][b];
      *(float4*)&out[((size_t)b * TT + t) * HS + u0 + ug * 4] = o;
    }
  }
}

// ---------------------------------------------------------------------------
extern "C" void kernel_launch(void* const* d_in, const int* in_sizes, int n_in,
                              void* d_out, int out_size, void* d_ws, size_t ws_size,
                              hipStream_t stream)
{
  const float* X   = (const float*)d_in[0];
  const float* mem = (const float*)d_in[1];
  const float* Wih = (const float*)d_in[2];
  const float* Whh = (const float*)d_in[3];
  const float* bih = (const float*)d_in[4];
  const float* bhh = (const float*)d_in[5];

  float* out = (float*)d_out;
  float* outmem = out + (size_t)BB * TT * HS;

  float* PG    = (float*)d_ws;                       // 512*2048*64 f32 = 256 MB
  uint32_t* hbp = (uint32_t*)(PG + (size_t)TT * R4H * BB);  // 2*16384 u32
  unsigned* bar = (unsigned*)(hbp + 2 * HB_STRIDE);  // 2048 u32

  hipMemsetAsync(bar, 0, 2048 * sizeof(unsigned), stream);
  init_h<<<dim3((HB_STRIDE + 255) / 256), dim3(256), 0, stream>>>(mem, hbp);
  pregemm<<<dim3(TT, 32), dim3(256), 0, stream>>>(X, Wih, bih, bhh, PG);
  lstm_persistent<<<dim3(256), dim3(512), 0, stream>>>(mem, Whh, PG, hbp, outmem, bar);
  transpose_out<<<dim3(TT, 8), dim3(256), 0, stream>>>(PG, out);
}

// Round 9
// 3394.342 us; speedup vs baseline: 3.1125x; 3.1125x over previous
//
#include <hip/hip_runtime.h>
#include <stdint.h>

#define TT 512
#define BB 64
#define II 256
#define HS 512          // H
#define HHALF 256       // HH
#define R4H 2048        // 4*H
#define HB_STRIDE 16384 // (HS/2)*BB u32 entries per h buffer

// ---------------------------------------------------------------------------
// Phase 1: PG[t][r][b] = (b_ih[r]+b_hh[r]) + sum_k W_ih[r][k] * X[b][t][k]
// ---------------------------------------------------------------------------
__global__ __launch_bounds__(256) void pregemm(
    const float* __restrict__ X,    // [B][T][I]
    const float* __restrict__ Wih,  // [4H][I]
    const float* __restrict__ bih,
    const float* __restrict__ bhh,
    float* __restrict__ PG)         // [T][4H][B]
{
  __shared__ __align__(16) float Xs[64][68];
  __shared__ __align__(16) float Ws[64][68];
  const int t = blockIdx.x;
  const int rbase = blockIdx.y * 64;
  const int tid = threadIdx.x;
  const int cg = tid & 15;
  const int rg = tid >> 4;

  float acc[4][4] = {};

  for (int k0 = 0; k0 < II; k0 += 64) {
    {
      int b = tid >> 2, kq = tid & 3;
      const float* src = X + ((size_t)b * TT + t) * II + k0 + kq * 16;
      #pragma unroll
      for (int i = 0; i < 16; i += 4) {
        float4 v = *(const float4*)(src + i);
        int kk = kq * 16 + i;
        Xs[kk + 0][b] = v.x; Xs[kk + 1][b] = v.y;
        Xs[kk + 2][b] = v.z; Xs[kk + 3][b] = v.w;
      }
    }
    {
      int r = tid >> 2, kq = tid & 3;
      const float* src = Wih + (size_t)(rbase + r) * II + k0 + kq * 16;
      #pragma unroll
      for (int i = 0; i < 16; i += 4) {
        float4 v = *(const float4*)(src + i);
        int kk = kq * 16 + i;
        Ws[kk + 0][r] = v.x; Ws[kk + 1][r] = v.y;
        Ws[kk + 2][r] = v.z; Ws[kk + 3][r] = v.w;
      }
    }
    __syncthreads();
    #pragma unroll 8
    for (int kk = 0; kk < 64; ++kk) {
      float4 a = *(const float4*)&Ws[kk][rg * 4];
      float4 x = *(const float4*)&Xs[kk][cg * 4];
      float av[4] = {a.x, a.y, a.z, a.w};
      float xv[4] = {x.x, x.y, x.z, x.w};
      #pragma unroll
      for (int i = 0; i < 4; ++i)
        #pragma unroll
        for (int j = 0; j < 4; ++j)
          acc[i][j] = fmaf(av[i], xv[j], acc[i][j]);
    }
    __syncthreads();
  }

  #pragma unroll
  for (int i = 0; i < 4; ++i) {
    int row = rbase + rg * 4 + i;
    float bias = bih[row] + bhh[row];
    float4 o;
    o.x = acc[i][0] + bias; o.y = acc[i][1] + bias;
    o.z = acc[i][2] + bias; o.w = acc[i][3] + bias;
    *(float4*)&PG[((size_t)t * R4H + row) * BB + cg * 4] = o;
  }
}

// ---------------------------------------------------------------------------
// bf16 round-to-nearest-even (h magnitudes are finite, |h|<=1; no NaN path)
// ---------------------------------------------------------------------------
__device__ __forceinline__ uint32_t bf16r(float f) {
  uint32_t u = __float_as_uint(f);
  u += 0x7fffu + ((u >> 16) & 1u);
  return u >> 16;
}

// init: hb[0][uh][b] = pack(bf16(mem[b][256+2uh]), bf16(mem[b][256+2uh+1]))
__global__ void init_h(const float* __restrict__ mem, uint32_t* __restrict__ hb)
{
  int idx = blockIdx.x * 256 + threadIdx.x;
  if (idx < HB_STRIDE) {
    int uh = idx >> 6, b = idx & 63;
    float lo = mem[(size_t)b * 1280 + 256 + 2 * uh];
    float hi = mem[(size_t)b * 1280 + 256 + 2 * uh + 1];
    hb[idx] = bf16r(lo) | (bf16r(hi) << 16);
  }
}

// ---------------------------------------------------------------------------
// Cross-XCD h hand-off (proven R6): relaxed agent-scope EXCHANGE stores
// (RMW performed at the IF coherence point; vmcnt(0) ack => globally
// visible) + relaxed agent-scope loads (bypass stale L1/L2). RELAXED =>
// no wbl2/inv sweeps (the 91 us/step cost that killed R1).
// ---------------------------------------------------------------------------
__device__ __forceinline__ void store_coh_u32(uint32_t* p, uint32_t v) {
  (void)__hip_atomic_exchange(p, v, __ATOMIC_RELAXED, __HIP_MEMORY_SCOPE_AGENT);
}
__device__ __forceinline__ uint32_t load_coh_u32(const uint32_t* p) {
  return __hip_atomic_load(p, __ATOMIC_RELAXED, __HIP_MEMORY_SCOPE_AGENT);
}

// ---------------------------------------------------------------------------
// Persistent LSTM. grid = 256 WGs x 512 threads; WG g owns units {2g, 2g+1}.
// lane = batch element; wave wu owns k-chunk [wu*64, wu*64+64).
// W broadcast mechanism (R8): the WG's W slice (8 rows x 512 k = 16 KB) is
// staged into LDS ONCE; inner loop reads it with ds_read_b128 at
// wave-uniform addresses = hardware broadcast, zero bank conflicts, on the
// LDS pipe (overlaps VALU). R6's readlane chain stalled on SGPR hazards;
// R7's global re-reads were per-lane flat loads (2.5x regression).
// h is bf16x2-packed. Barrier: hierarchical monotonic, relaxed agent RMWs.
// ---------------------------------------------------------------------------
__global__ __launch_bounds__(512) void lstm_persistent(
    const float* __restrict__ mem,   // [B][1280]
    const float* __restrict__ Whh,   // [4H][H]
    float* __restrict__ PG,          // [T][4H][B]
    uint32_t* __restrict__ hb,       // [2][HS/2][B] packed bf16x2
    float* __restrict__ outmem,      // [B][1280]
    unsigned* __restrict__ bar)      // grpcnt[8]@stride64, cnt2@1024, gen@1088
{
  const int g = blockIdx.x;
  const int u0 = g * 2;
  const int tid = threadIdx.x;
  const int wu = __builtin_amdgcn_readfirstlane(tid >> 6);  // wave id, uniform
  const int lane = tid & 63;

  __shared__ __align__(16) float Wlds[8][512];   // 16 KB, static W slice
  __shared__ float part[8][64][9];
  __shared__ float gsum[8][64];

  unsigned* grpcnt = bar + (g >> 5) * 64;
  unsigned* cnt2   = bar + 1024;
  unsigned* gen    = bar + 1088;

  // ---- stage W slice into LDS once (coalesced: one 2KB row per pass) ----
  #pragma unroll
  for (int r = 0; r < 8; ++r) {
    int row = (r >> 1) * HS + u0 + (r & 1);
    Wlds[r][tid] = Whh[(size_t)row * HS + tid];
  }
  __syncthreads();

  // per-batch state: tid<64 owns batch b=tid, BOTH units {u0, u0+1}
  float c0 = 0.f, c1 = 0.f, m0 = 0.f, m1 = 0.f, h0l = 0.f, h1l = 0.f;
  if (tid < 64) {
    c0 = mem[(size_t)tid * 1280 + 768 + u0];
    c1 = mem[(size_t)tid * 1280 + 768 + u0 + 1];
    if (u0 < HHALF) {
      m0 = mem[(size_t)tid * 1280 + u0];
      m1 = mem[(size_t)tid * 1280 + u0 + 1];
    }
  }

  const int rr = tid >> 6;
  const int grow = (rr >> 1) * HS + u0 + (rr & 1);
  const int kbase = wu * 64;

  for (int t = 0; t < TT; ++t) {
    const uint32_t* hcur = hb + (size_t)(t & 1) * HB_STRIDE;
    float pg = PG[((size_t)t * R4H + grow) * BB + lane];

    // ---- fetch this wave's packed h chunk (coherent, all in flight) ----
    const uint32_t* hp = hcur + (size_t)(wu * 32) * BB + lane;
    uint32_t hpk[32];
    #pragma unroll
    for (int j = 0; j < 32; ++j) hpk[j] = load_coh_u32(hp + (size_t)j * BB);
    float hreg[64];
    #pragma unroll
    for (int j = 0; j < 32; ++j) {
      hreg[2 * j]     = __int_as_float(hpk[j] << 16);
      hreg[2 * j + 1] = __int_as_float(hpk[j] & 0xffff0000u);
    }

    // ---- recurrent GEMM: W via LDS broadcast (b128), h in VGPRs ----
    float acc[8] = {0, 0, 0, 0, 0, 0, 0, 0};
    #pragma unroll
    for (int k4 = 0; k4 < 16; ++k4) {
      float4 wv[8];
      #pragma unroll
      for (int r = 0; r < 8; ++r)
        wv[r] = *(const float4*)&Wlds[r][kbase + k4 * 4];
      #pragma unroll
      for (int j = 0; j < 4; ++j) {
        float h = hreg[k4 * 4 + j];
        #pragma unroll
        for (int r = 0; r < 8; ++r)
          acc[r] = fmaf(((const float*)&wv[r])[j], h, acc[r]);
      }
    }
    #pragma unroll
    for (int r = 0; r < 8; ++r) part[r][lane][wu] = acc[r];
    __syncthreads();

    // ---- reduce 8 k-chunk partials + pg ----
    float s = pg;
    #pragma unroll
    for (int ww = 0; ww < 8; ++ww) s += part[rr][lane][ww];
    gsum[rr][lane] = s;
    __syncthreads();

    // ---- elementwise LSTM cells (both units) + cmax (tid < 64) ----
    if (tid < 64) {
      const int b = tid;
      float gi0 = gsum[0][b], gf0 = gsum[2][b], gg0 = gsum[4][b], go0 = gsum[6][b];
      float gi1 = gsum[1][b], gf1 = gsum[3][b], gg1 = gsum[5][b], go1 = gsum[7][b];
      float si0 = 1.f / (1.f + __expf(-gi0));
      float sf0 = 1.f / (1.f + __expf(-gf0));
      float so0 = 1.f / (1.f + __expf(-go0));
      float si1 = 1.f / (1.f + __expf(-gi1));
      float sf1 = 1.f / (1.f + __expf(-gf1));
      float so1 = 1.f / (1.f + __expf(-go1));
      c0 = sf0 * c0 + si0 * tanhf(gg0);
      c1 = sf1 * c1 + si1 * tanhf(gg1);
      float h0 = so0 * tanhf(c0);
      float h1 = so1 * tanhf(c1);
      h0l = h0; h1l = h1;
      store_coh_u32(&hb[(size_t)((t + 1) & 1) * HB_STRIDE + (size_t)g * 64 + b],
                    bf16r(h0) | (bf16r(h1) << 16));
      float out0, out1;
      if (u0 < HHALF) { m0 = fmaxf(m0, h0); m1 = fmaxf(m1, h1); out0 = m0; out1 = m1; }
      else            { out0 = h0; out1 = h1; }
      PG[((size_t)t * R4H + u0) * BB + b]     = out0;  // same-WG rows only
      PG[((size_t)t * R4H + u0 + 1) * BB + b] = out1;
    }

    // ---- device barrier: release = vmcnt(0) on the exchange h-stores ----
    asm volatile("s_waitcnt vmcnt(0)" ::: "memory");
    __syncthreads();
    if (tid == 0) {
      unsigned tgt1 = 32u * (unsigned)(t + 1);
      unsigned a = __hip_atomic_fetch_add(grpcnt, 1u, __ATOMIC_RELAXED,
                                          __HIP_MEMORY_SCOPE_AGENT);
      if (a == tgt1 - 1u) {
        unsigned b2 = __hip_atomic_fetch_add(cnt2, 1u, __ATOMIC_RELAXED,
                                             __HIP_MEMORY_SCOPE_AGENT);
        if (b2 == 8u * (unsigned)(t + 1) - 1u)
          (void)__hip_atomic_exchange(gen, (unsigned)(t + 1), __ATOMIC_RELAXED,
                                      __HIP_MEMORY_SCOPE_AGENT);
      }
      // failsafe cap: fast wrong-answer instead of a hang; expected wait ~us.
      int spins = 0;
      while (__hip_atomic_load(gen, __ATOMIC_RELAXED,
                               __HIP_MEMORY_SCOPE_AGENT) < (unsigned)(t + 1)) {
        __builtin_amdgcn_s_sleep(2);
        if (++spins > (1 << 16)) break;
      }
    }
    __syncthreads();
  }

  if (tid < 64) {
    outmem[(size_t)tid * 1280 + 256 + u0]     = h0l;
    outmem[(size_t)tid * 1280 + 256 + u0 + 1] = h1l;
    outmem[(size_t)tid * 1280 + 768 + u0]     = c0;
    outmem[(size_t)tid * 1280 + 768 + u0 + 1] = c1;
    if (u0 < HHALF) {
      outmem[(size_t)tid * 1280 + u0]     = m0;
      outmem[(size_t)tid * 1280 + u0 + 1] = m1;
    }
  }
}

// ---------------------------------------------------------------------------
// Phase 3: out[b][t][u] = PG[t][u][b]  (u < 512)
// ---------------------------------------------------------------------------
__global__ __launch_bounds__(256) void transpose_out(
    const float* __restrict__ PG, float* __restrict__ out)
{
  __shared__ __align__(16) float tileS[64][68];
  const int t = blockIdx.x;
  const int u0 = blockIdx.y * 64;
  const int tid = threadIdx.x;

  {
    int cg = tid & 15, rg = tid >> 4;
    const float* src = PG + (size_t)t * R4H * BB + (size_t)u0 * BB;
    #pragma unroll
    for (int i = 0; i < 4; ++i) {
      int u = rg * 4 + i;
      float4 v = *(const float4*)(src + (size_t)u * BB + cg * 4);
      *(float4*)&tileS[u][cg * 4] = v;
    }
  }
  __syncthreads();
  {
    int ug = tid & 15, bg = tid >> 4;
    #pragma unroll
    for (int i = 0; i < 4; ++i) {
      int b = bg * 4 + i;
      float4 o;
      o.x = tileS[ug * 4 + 0][b];
      o.y = tileS[ug * 4 + 1][b];
      o.z = tileS[ug * 4 + 2][b];
      o.w = tileS[ug * 4 + 3][b];
      *(float4*)&out[((size_t)b * TT + t) * HS + u0 + ug * 4] = o;
    }
  }
}

// ---------------------------------------------------------------------------
extern "C" void kernel_launch(void* const* d_in, const int* in_sizes, int n_in,
                              void* d_out, int out_size, void* d_ws, size_t ws_size,
                              hipStream_t stream)
{
  const float* X   = (const float*)d_in[0];
  const float* mem = (const float*)d_in[1];
  const float* Wih = (const float*)d_in[2];
  const float* Whh = (const float*)d_in[3];
  const float* bih = (const float*)d_in[4];
  const float* bhh = (const float*)d_in[5];

  float* out = (float*)d_out;
  float* outmem = out + (size_t)BB * TT * HS;

  float* PG    = (float*)d_ws;                       // 512*2048*64 f32 = 256 MB
  uint32_t* hbp = (uint32_t*)(PG + (size_t)TT * R4H * BB);  // 2*16384 u32
  unsigned* bar = (unsigned*)(hbp + 2 * HB_STRIDE);  // 2048 u32

  hipMemsetAsync(bar, 0, 2048 * sizeof(unsigned), stream);
  init_h<<<dim3((HB_STRIDE + 255) / 256), dim3(256), 0, stream>>>(mem, hbp);
  pregemm<<<dim3(TT, 32), dim3(256), 0, stream>>>(X, Wih, bih, bhh, PG);
  lstm_persistent<<<dim3(256), dim3(512), 0, stream>>>(mem, Whh, PG, hbp, outmem, bar);
  transpose_out<<<dim3(TT, 8), dim3(256), 0, stream>>>(PG, out);
}